// Round 2
// baseline (33192.780 us; speedup 1.0000x reference)
//
#include <hip/hip_runtime.h>
#include <hip/hip_bf16.h>

using bf16 = __hip_bfloat16;

typedef __attribute__((ext_vector_type(8))) short short8;
typedef __attribute__((ext_vector_type(4))) float floatx4;

static constexpr int B_ = 256;   // batch
static constexpr int T_ = 128;   // time steps

__device__ __forceinline__ float bf2f(bf16 v) { return __bfloat162float(v); }
__device__ __forceinline__ bf16  f2bf(float v) { return __float2bfloat16(v); }

enum { MODE_GATES = 0, MODE_CAND = 1, MODE_DENSE = 2 };

// fp32 -> bf16 bulk convert, 8 elements/thread (n8 = n/8)
__global__ __launch_bounds__(256) void cvt_k(const float* __restrict__ src,
                                             bf16* __restrict__ dst, int n8)
{
    int i = blockIdx.x * 256 + threadIdx.x;
    if (i >= n8) return;
    const float* s = src + (size_t)i * 8;
    float4 a = *(const float4*)s;
    float4 b = *(const float4*)(s + 4);
    bf16 t[8] = {f2bf(a.x), f2bf(a.y), f2bf(a.z), f2bf(a.w),
                 f2bf(b.x), f2bf(b.y), f2bf(b.z), f2bf(b.w)};
    *(uint4*)(dst + (size_t)i * 8) = *(uint4*)t;
}

// C = [A0 | A1] @ Bw  (+ bias, + epilogue), M = 256 fixed.
// A row-major bf16 activations, split at K1 (segment boundaries are multiples
// of BK=32 so each K-tile reads exactly one segment). Bw row-major bf16 [Ktot x N].
// Tile: 64x64/block, 256 threads = 4 waves, each wave 32x32 via 2x2
// mfma_f32_16x16x32_bf16.
template <int MODE>
__global__ __launch_bounds__(256) void gemm_k(
    const bf16* __restrict__ A0, int ldA0, int K1,
    const bf16* __restrict__ A1, int ldA1, int Ktot,
    const bf16* __restrict__ Bw, int ldB,
    const bf16* __restrict__ bias,
    int out,                                   // layer hidden size
    float* __restrict__ hf, bf16* __restrict__ hb,
    bf16* __restrict__ rh, float* __restrict__ zb,
    const int* __restrict__ lens, int t,
    float* __restrict__ yout)
{
    __shared__ __align__(16) bf16 As[64 * 40];   // [row][k], ld 40 (pad)
    __shared__ __align__(16) bf16 Bs[64 * 40];   // [n][k] transposed, ld 40

    const int tid  = threadIdx.x;
    const int bm   = blockIdx.y * 64;
    const int bn   = blockIdx.x * 64;
    const int lane = tid & 63;
    const int wave = tid >> 6;
    const int wm   = (wave >> 1) * 32;
    const int wn   = (wave & 1) * 32;
    const int quad = lane >> 4;
    const int l16  = lane & 15;

    floatx4 acc[2][2] = {};

    // staging indices
    const int ar = tid >> 2, ak = (tid & 3) * 8;  // A: 64 rows x 32 k
    const int bk = tid >> 3, bn0 = (tid & 7) * 8; // B: 32 k x 64 n

    for (int k0 = 0; k0 < Ktot; k0 += 32) {
        // ---- stage A (coalesced 16B loads, 16B LDS stores) ----
        const bf16* ap;
        if (k0 < K1) ap = A0 + (size_t)(bm + ar) * ldA0 + (k0 + ak);
        else         ap = A1 + (size_t)(bm + ar) * ldA1 + (k0 - K1 + ak);
        uint4 av = *(const uint4*)ap;
        *(uint4*)&As[ar * 40 + ak] = av;

        // ---- stage B transposed ----
        uint4 bv = *(const uint4*)(Bw + (size_t)(k0 + bk) * ldB + bn + bn0);
        bf16 tmp[8];
        *(uint4*)tmp = bv;
#pragma unroll
        for (int i = 0; i < 8; ++i) Bs[(bn0 + i) * 40 + bk] = tmp[i];

        __syncthreads();

        short8 af0 = *(const short8*)&As[(wm + l16) * 40 + quad * 8];
        short8 af1 = *(const short8*)&As[(wm + 16 + l16) * 40 + quad * 8];
        short8 bw0 = *(const short8*)&Bs[(wn + l16) * 40 + quad * 8];
        short8 bw1 = *(const short8*)&Bs[(wn + 16 + l16) * 40 + quad * 8];

        acc[0][0] = __builtin_amdgcn_mfma_f32_16x16x32_bf16(af0, bw0, acc[0][0], 0, 0, 0);
        acc[0][1] = __builtin_amdgcn_mfma_f32_16x16x32_bf16(af0, bw1, acc[0][1], 0, 0, 0);
        acc[1][0] = __builtin_amdgcn_mfma_f32_16x16x32_bf16(af1, bw0, acc[1][0], 0, 0, 0);
        acc[1][1] = __builtin_amdgcn_mfma_f32_16x16x32_bf16(af1, bw1, acc[1][1], 0, 0, 0);

        __syncthreads();
    }

    // ---- epilogue ----
#pragma unroll
    for (int tm = 0; tm < 2; ++tm)
#pragma unroll
        for (int tn = 0; tn < 2; ++tn)
#pragma unroll
            for (int r = 0; r < 4; ++r) {
                const int row = bm + wm + tm * 16 + quad * 4 + r;
                const int col = bn + wn + tn * 16 + l16;
                float v = acc[tm][tn][r] + bf2f(bias[col]);
                if (MODE == MODE_GATES) {
                    float s = 1.f / (1.f + __expf(-v));
                    if (col < out) {
                        size_t idx = (size_t)row * out + col;
                        rh[idx] = f2bf(s * hf[idx]);     // r * h  (h from t-1, fp32)
                    } else {
                        zb[(size_t)row * out + (col - out)] = s;
                    }
                } else if (MODE == MODE_CAND) {
                    float c = tanhf(v);
                    size_t idx = (size_t)row * out + col;
                    float zv = zb[idx];
                    float ho = hf[idx];
                    float hn = (t < lens[row]) ? (zv * ho + (1.f - zv) * c) : ho;
                    hf[idx] = hn;
                    hb[idx] = f2bf(hn);
                } else {
                    yout[(size_t)row * 512 + col] = tanhf(v);
                }
            }
}

// emb_all[t][b][0:32] = bf16(emb_table[seq[b][t]])
__global__ __launch_bounds__(256) void embed_k(const int* __restrict__ seq,
                                               const float* __restrict__ tab,
                                               bf16* __restrict__ emb_all)
{
    int c = blockIdx.x * 256 + threadIdx.x;  // T_*B_*4 chunks of 8 elems
    int t = c >> 10;                         // B_*4 = 1024 chunks per step
    int r = c & 1023;
    int b = r >> 2, i = r & 3;
    int tok = seq[b * T_ + t];
    const float* s = tab + (size_t)tok * 32 + i * 8;
    bf16 tmp[8];
#pragma unroll
    for (int j = 0; j < 8; ++j) tmp[j] = f2bf(s[j]);
    *(uint4*)(emb_all + ((size_t)t * B_ + b) * 32 + i * 8) = *(uint4*)tmp;
}

// cc[b][0:3584] = bf16(concat(h0[b], h1[b], h2[b]))
__global__ __launch_bounds__(256) void concat_k(const float* __restrict__ h0,
                                                const float* __restrict__ h1,
                                                const float* __restrict__ h2,
                                                bf16* __restrict__ cc)
{
    int c = blockIdx.x * 256 + threadIdx.x;  // 256*448 chunks of 8
    int b = c / 448;
    int j = (c % 448) * 8;
    const float* src;
    if (j < 512)        src = h0 + (size_t)b * 512 + j;
    else if (j < 1536)  src = h1 + (size_t)b * 1024 + (j - 512);
    else                src = h2 + (size_t)b * 2048 + (j - 1536);
    bf16 tmp[8];
#pragma unroll
    for (int i = 0; i < 8; ++i) tmp[i] = f2bf(src[i]);
    *(uint4*)(cc + (size_t)b * 3584 + j) = *(uint4*)tmp;
}

extern "C" void kernel_launch(void* const* d_in, const int* in_sizes, int n_in,
                              void* d_out, int out_size, void* d_ws, size_t ws_size,
                              hipStream_t stream)
{
    const int*   seq  = (const int*)d_in[0];
    const int*   lens = (const int*)d_in[1];
    const float* tab  = (const float*)d_in[2];
    const float* gkF[3] = {(const float*)d_in[3], (const float*)d_in[7], (const float*)d_in[11]};
    const float* gbF[3] = {(const float*)d_in[4], (const float*)d_in[8], (const float*)d_in[12]};
    const float* ckF[3] = {(const float*)d_in[5], (const float*)d_in[9], (const float*)d_in[13]};
    const float* cbF[3] = {(const float*)d_in[6], (const float*)d_in[10], (const float*)d_in[14]};
    const float* dwF = (const float*)d_in[15];
    const float* dbF = (const float*)d_in[16];
    float* y = (float*)d_out;

    const int outs[3] = {512, 1024, 2048};
    const int ins[3]  = {32, 512, 1024};

    char* w = (char*)d_ws;
    auto alloc = [&](size_t bytes) -> void* {
        void* p = (void*)w;
        w += (bytes + 255) & ~(size_t)255;
        return p;
    };

    // bf16 copies of weights/biases (converted every call; ws is re-poisoned)
    bf16 *gk[3], *gb[3], *ck[3], *cb[3], *dw, *db;
    int gkN[3], ckN[3];
    for (int l = 0; l < 3; ++l) {
        gkN[l] = (ins[l] + outs[l]) * 2 * outs[l];
        ckN[l] = (ins[l] + outs[l]) * outs[l];
        gk[l] = (bf16*)alloc((size_t)gkN[l] * sizeof(bf16));
        ck[l] = (bf16*)alloc((size_t)ckN[l] * sizeof(bf16));
        gb[l] = (bf16*)alloc((size_t)2 * outs[l] * sizeof(bf16));
        cb[l] = (bf16*)alloc((size_t)outs[l] * sizeof(bf16));
    }
    dw = (bf16*)alloc((size_t)3584 * 512 * sizeof(bf16));
    db = (bf16*)alloc((size_t)512 * sizeof(bf16));

    bf16* emb_all = (bf16*)alloc((size_t)T_ * B_ * 32 * sizeof(bf16));
    float* hf[3]; bf16* hb[3]; bf16* rh[3]; float* zb[3];
    for (int l = 0; l < 3; ++l) {
        hf[l] = (float*)alloc((size_t)B_ * outs[l] * sizeof(float));
        hb[l] = (bf16*)alloc((size_t)B_ * outs[l] * sizeof(bf16));
        rh[l] = (bf16*)alloc((size_t)B_ * outs[l] * sizeof(bf16));
        zb[l] = (float*)alloc((size_t)B_ * outs[l] * sizeof(float));
    }
    bf16* cc = (bf16*)alloc((size_t)B_ * 3584 * sizeof(bf16));

    auto cvt = [&](const float* s, bf16* d, int n) {
        int n8 = n / 8;
        cvt_k<<<(n8 + 255) / 256, 256, 0, stream>>>(s, d, n8);
    };
    for (int l = 0; l < 3; ++l) {
        cvt(gkF[l], gk[l], gkN[l]);
        cvt(ckF[l], ck[l], ckN[l]);
        cvt(gbF[l], gb[l], 2 * outs[l]);
        cvt(cbF[l], cb[l], outs[l]);
    }
    cvt(dwF, dw, 3584 * 512);
    cvt(dbF, db, 512);

    // zero initial states (ws is poisoned before every call)
    for (int l = 0; l < 3; ++l) {
        hipMemsetAsync(hf[l], 0, (size_t)B_ * outs[l] * sizeof(float), stream);
        hipMemsetAsync(hb[l], 0, (size_t)B_ * outs[l] * sizeof(bf16), stream);
    }

    embed_k<<<T_ * B_ * 4 / 256, 256, 0, stream>>>(seq, tab, emb_all);

    for (int t = 0; t < T_; ++t) {
        const bf16* x0 = emb_all + (size_t)t * B_ * 32;
        // layer 0
        gemm_k<MODE_GATES><<<dim3(2 * outs[0] / 64, 4), 256, 0, stream>>>(
            x0, 32, 32, hb[0], outs[0], ins[0] + outs[0], gk[0], 2 * outs[0], gb[0],
            outs[0], hf[0], nullptr, rh[0], zb[0], nullptr, 0, nullptr);
        gemm_k<MODE_CAND><<<dim3(outs[0] / 64, 4), 256, 0, stream>>>(
            x0, 32, 32, rh[0], outs[0], ins[0] + outs[0], ck[0], outs[0], cb[0],
            outs[0], hf[0], hb[0], nullptr, zb[0], lens, t, nullptr);
        // layer 1
        gemm_k<MODE_GATES><<<dim3(2 * outs[1] / 64, 4), 256, 0, stream>>>(
            hb[0], outs[0], ins[1], hb[1], outs[1], ins[1] + outs[1], gk[1], 2 * outs[1], gb[1],
            outs[1], hf[1], nullptr, rh[1], zb[1], nullptr, 0, nullptr);
        gemm_k<MODE_CAND><<<dim3(outs[1] / 64, 4), 256, 0, stream>>>(
            hb[0], outs[0], ins[1], rh[1], outs[1], ins[1] + outs[1], ck[1], outs[1], cb[1],
            outs[1], hf[1], hb[1], nullptr, zb[1], lens, t, nullptr);
        // layer 2
        gemm_k<MODE_GATES><<<dim3(2 * outs[2] / 64, 4), 256, 0, stream>>>(
            hb[1], outs[1], ins[2], hb[2], outs[2], ins[2] + outs[2], gk[2], 2 * outs[2], gb[2],
            outs[2], hf[2], nullptr, rh[2], zb[2], nullptr, 0, nullptr);
        gemm_k<MODE_CAND><<<dim3(outs[2] / 64, 4), 256, 0, stream>>>(
            hb[1], outs[1], ins[2], rh[2], outs[2], ins[2] + outs[2], ck[2], outs[2], cb[2],
            outs[2], hf[2], hb[2], nullptr, zb[2], lens, t, nullptr);
    }

    concat_k<<<B_ * 3584 / 8 / 256, 256, 0, stream>>>(hf[0], hf[1], hf[2], cc);
    gemm_k<MODE_DENSE><<<dim3(512 / 64, 4), 256, 0, stream>>>(
        cc, 3584, 3584, cc, 3584, 3584, dw, 512, db,
        512, nullptr, nullptr, nullptr, nullptr, nullptr, 0, y);
}